// Round 15
// baseline (208.648 us; speedup 1.0000x reference)
//
#include <hip/hip_runtime.h>
#include <hip/hip_fp16.h>
#include <math.h>

// ---------------------------------------------------------------------------
// 3-layer GCN (PyG GCNConv semantics): per layer
//   h = x @ W ; out[v] = dinv[v]*(dinv[v]*h[v] + sum_e dinv[s]*h[s]) + b
// CSR + dinv built once. All hidden state fp16.
// Build: countrank (ONE fabric-atomic pass, rank = returned old count) ->
// scan -> fillr (atomic-free coalesced scatter).
// GEMM = MFMA f16 16x16x32 swapped operands; W pre-converted to fragments.
// mgemm<8> emits h as TWO half-arrays Hh[half][node][64] (64 feats each).
// agg128h: wave = (node, half), half = blockIdx&1 -> halves pinned to
// disjoint XCD sets (round-robin block->XCD), halving per-XCD compulsory
// H traffic (FETCH 94MB -> ~55MB). 8 edge slots x 8 feat chunks,
// v_pk_fma_f16 accumulation, packed reduce, fp32 epilogue + __expf ELU.
// agg64: unchanged (row-major 64, pk accumulation).
// ---------------------------------------------------------------------------

#define NFEAT_IN 128
#define SCAN_CHUNK 2048

typedef _Float16 f16x8 __attribute__((ext_vector_type(8)));
typedef float f32x4 __attribute__((ext_vector_type(4)));

// zero cnt; also zero the 16 esw padding entries past E
__global__ void zero_kernel(int4* __restrict__ p, int n4, int4* __restrict__ eswpad) {
    int i = blockIdx.x * blockDim.x + threadIdx.x;
    int4 z; z.x = z.y = z.z = z.w = 0;
    if (i < n4) p[i] = z;
    if (i < 8) eswpad[i] = z;
}

// count + rank in one pass: rank[i] = old cnt[dst[i]] (atomic return value)
__global__ __launch_bounds__(256) void countrank_kernel(const int* __restrict__ dst,
                                                        int* __restrict__ cnt,
                                                        int* __restrict__ rank, int E) {
    int i = blockIdx.x * blockDim.x + threadIdx.x;
    int base = i * 4;
    if (base + 4 <= E) {
        int4 d = *(const int4*)&dst[base];
        int4 r;
        r.x = atomicAdd(&cnt[d.x], 1);
        r.y = atomicAdd(&cnt[d.y], 1);
        r.z = atomicAdd(&cnt[d.z], 1);
        r.w = atomicAdd(&cnt[d.w], 1);
        *(int4*)&rank[base] = r;
    } else {
        for (int k = base; k < E; ++k) rank[k] = atomicAdd(&cnt[dst[k]], 1);
    }
}

__global__ __launch_bounds__(256) void reduce_kernel(const int* __restrict__ cnt,
                                                     int* __restrict__ bsum, int n) {
    __shared__ int wtot[4];
    int b = blockIdx.x, t = threadIdx.x;
    int base = b * SCAN_CHUNK + t * 8;
    int s = 0;
    if (base + 8 <= n) {
        int4 a = *(const int4*)&cnt[base];
        int4 c = *(const int4*)&cnt[base + 4];
        s = a.x + a.y + a.z + a.w + c.x + c.y + c.z + c.w;
    } else {
        for (int i = 0; i < 8; ++i) if (base + i < n) s += cnt[base + i];
    }
    int lane = t & 63, wid = t >> 6;
    #pragma unroll
    for (int off = 32; off > 0; off >>= 1) s += __shfl_down(s, off, 64);
    if (lane == 0) wtot[wid] = s;
    __syncthreads();
    if (t == 0) bsum[b] = wtot[0] + wtot[1] + wtot[2] + wtot[3];
}

// local scan within chunk; block derives its own cross-chunk base from bsum
// (nb <= 64); last block writes offs[n]. Writes offs, dinv.
__global__ __launch_bounds__(256) void scan3_kernel(const int* __restrict__ cnt,
                                                    const int* __restrict__ bsum,
                                                    int* __restrict__ offs,
                                                    float* __restrict__ dinv,
                                                    int n, int nb) {
    __shared__ int wtot[4];
    __shared__ int sbase;
    int b = blockIdx.x, t = threadIdx.x;
    if (t < 64) {
        int val = (t < nb) ? bsum[t] : 0;
        int pre = (t < b) ? val : 0;
        int tot = val;
        #pragma unroll
        for (int off = 32; off > 0; off >>= 1) {
            pre += __shfl_down(pre, off, 64);
            tot += __shfl_down(tot, off, 64);
        }
        if (t == 0) {
            sbase = pre;
            if (b == nb - 1) offs[n] = tot;
        }
    }
    int base = b * SCAN_CHUNK + t * 8;
    int v[8];
    #pragma unroll
    for (int i = 0; i < 8; ++i) v[i] = (base + i < n) ? cnt[base + i] : 0;
    int psum[8], s = 0;
    #pragma unroll
    for (int i = 0; i < 8; ++i) { psum[i] = s; s += v[i]; }
    int lane = t & 63, wid = t >> 6;
    int inc = s;
    #pragma unroll
    for (int off = 1; off < 64; off <<= 1) {
        int tt = __shfl_up(inc, off, 64);
        if (lane >= off) inc += tt;
    }
    if (lane == 63) wtot[wid] = inc;
    __syncthreads();
    int wb = 0;
    for (int w = 0; w < wid; ++w) wb += wtot[w];
    int tbase = sbase + wb + (inc - s);
    #pragma unroll
    for (int i = 0; i < 8; ++i) {
        if (base + i < n) {
            offs[base + i] = tbase + psum[i];
            dinv[base + i] = rsqrtf((float)(v[i] + 1));  // +1 self-loop
        }
    }
}

// atomic-free scatter: p = offs[dst] + rank; payload {src, packed half2(w,w)}
__global__ __launch_bounds__(256) void fillr_kernel(const int* __restrict__ src,
                                                    const int* __restrict__ dst,
                                                    const int* __restrict__ rank,
                                                    const int* __restrict__ offs,
                                                    const float* __restrict__ dinv,
                                                    int2* __restrict__ esw, int E) {
    int i = blockIdx.x * blockDim.x + threadIdx.x;
    int base = i * 4;
    if (base + 4 <= E) {
        int4 d = *(const int4*)&dst[base];
        int4 r = *(const int4*)&rank[base];
        int4 s = *(const int4*)&src[base];
        int p0 = offs[d.x] + r.x;
        int p1 = offs[d.y] + r.y;
        int p2 = offs[d.z] + r.z;
        int p3 = offs[d.w] + r.w;
        float w0 = dinv[s.x], w1 = dinv[s.y], w2 = dinv[s.z], w3 = dinv[s.w];
        __half2 h0 = __floats2half2_rn(w0, w0);
        __half2 h1 = __floats2half2_rn(w1, w1);
        __half2 h2 = __floats2half2_rn(w2, w2);
        __half2 h3 = __floats2half2_rn(w3, w3);
        int2 e0; e0.x = s.x; e0.y = *(int*)&h0;
        int2 e1; e1.x = s.y; e1.y = *(int*)&h1;
        int2 e2; e2.x = s.z; e2.y = *(int*)&h2;
        int2 e3; e3.x = s.w; e3.y = *(int*)&h3;
        esw[p0] = e0; esw[p1] = e1; esw[p2] = e2; esw[p3] = e3;
    } else {
        for (int k = base; k < E; ++k) {
            int d = dst[k];
            int p = offs[d] + rank[k];
            int s = src[k];
            float w = dinv[s];
            __half2 h = __floats2half2_rn(w, w);
            int2 e; e.x = s; e.y = *(int*)&h;
            esw[p] = e;
        }
    }
}

// x fp32 row-major -> fragment-chunk fp16 layout
__global__ __launch_bounds__(256) void convx_kernel(const float* __restrict__ x,
                                                    f16x8* __restrict__ Xf, int nchunk) {
    int i = blockIdx.x * blockDim.x + threadIdx.x;
    if (i >= nchunk) return;
    int m = i >> 4, kc = i & 15;
    float4 a = *(const float4*)&x[(size_t)m * 128 + kc * 8];
    float4 b = *(const float4*)&x[(size_t)m * 128 + kc * 8 + 4];
    f16x8 v;
    v[0] = (_Float16)a.x; v[1] = (_Float16)a.y; v[2] = (_Float16)a.z; v[3] = (_Float16)a.w;
    v[4] = (_Float16)b.x; v[5] = (_Float16)b.y; v[6] = (_Float16)b.z; v[7] = (_Float16)b.w;
    int kt = kc >> 2, sub = kc & 3;
    Xf[(size_t)((m >> 4) * 4 + kt) * 64 + sub * 16 + (m & 15)] = v;
}

// All three W -> fp16 A-fragment arrays in ONE dispatch.
__global__ void wfrag_kernel(const float* __restrict__ W1, const float* __restrict__ W2,
                             const float* __restrict__ W3, f16x8* __restrict__ wf1,
                             f16x8* __restrict__ wf2, f16x8* __restrict__ wf3) {
    int b = blockIdx.x;
    const float* W; f16x8* Wf; int NT;
    if (b < 8)       { W = W1; Wf = wf1; NT = 8; }
    else if (b < 16) { W = W2; Wf = wf2; NT = 8; b -= 8; }
    else             { W = W3; Wf = wf3; NT = 4; b -= 16; }
    int c = b * 256 + threadIdx.x;
    if (c >= NT * 256) return;
    int BN = NT * 16;
    int nt = c >> 8;
    int kt = (c >> 6) & 3;
    int l = c & 63;
    int n = nt * 16 + (l & 15);
    int k0 = kt * 32 + (l >> 4) * 8;
    f16x8 v;
    #pragma unroll
    for (int j = 0; j < 8; ++j) v[j] = (_Float16)W[(size_t)(k0 + j) * BN + n];
    Wf[c] = v;
}

// MFMA GEMM: X(frag) @ Wf(frag). 2 mtiles/wave.
// Output rows of 64 fp16: half (nt>>2) at byte offset hstride (elements).
// NT=8 -> two half-arrays Hh[half][m][64]; NT=4 -> single row-major 64 (h=0).
template <int NT>  // BN = NT*16
__global__ __launch_bounds__(256) void mgemm_kernel(const f16x8* __restrict__ Xf,
                                                    const f16x8* __restrict__ Wg,
                                                    __half* __restrict__ Y, int mtiles,
                                                    size_t hstride) {
    __shared__ f16x8 Wf[NT * 4 * 64];
    int t = threadIdx.x;
    #pragma unroll
    for (int i = 0; i < NT; ++i) Wf[t + i * 256] = Wg[t + i * 256];
    __syncthreads();
    int lane = t & 63;
    int mt0 = blockIdx.x * 8 + (t >> 6) * 2;
    #pragma unroll
    for (int it = 0; it < 2; ++it) {
        int mtile = mt0 + it;
        if (mtile >= mtiles) continue;
        const f16x8* xb = Xf + (size_t)mtile * 4 * 64;
        f16x8 bf[4];
        #pragma unroll
        for (int kt = 0; kt < 4; ++kt) bf[kt] = xb[kt * 64 + lane];
        f32x4 acc[NT];
        #pragma unroll
        for (int nt = 0; nt < NT; ++nt) acc[nt] = (f32x4){0.f, 0.f, 0.f, 0.f};
        #pragma unroll
        for (int kt = 0; kt < 4; ++kt) {
            #pragma unroll
            for (int nt = 0; nt < NT; ++nt) {
                f16x8 af = Wf[(nt * 4 + kt) * 64 + lane];
                acc[nt] = __builtin_amdgcn_mfma_f32_16x16x32_f16(af, bf[kt], acc[nt], 0, 0, 0);
            }
        }
        int m = mtile * 16 + (lane & 15);
        int nc0 = (lane >> 4) * 4;
        #pragma unroll
        for (int nt = 0; nt < NT; ++nt) {
            union { __half2 h2[2]; uint2 u; } pk;
            pk.h2[0] = __floats2half2_rn(acc[nt][0], acc[nt][1]);
            pk.h2[1] = __floats2half2_rn(acc[nt][2], acc[nt][3]);
            *(uint2*)&Y[(size_t)(nt >> 2) * hstride + (size_t)m * 64 + (nt & 3) * 16 + nc0] = pk.u;
        }
    }
}

// half-split CSR aggregation, 128 feats as 2 x 64-feat half-arrays.
// wave = (node, half); half = blockIdx&1 -> halves on disjoint XCD sets.
// 8 edge slots x 8 feat chunks; v_pk_fma_f16; packed 3-level reduce;
// fp32 epilogue + __expf ELU. Output: fragment-chunk fp16 for next GEMM.
__global__ __launch_bounds__(256) void agg128h_kernel(const __half* __restrict__ H,
                                                      const int* __restrict__ offs,
                                                      const int2* __restrict__ esw,
                                                      const float* __restrict__ dinv,
                                                      const float* __restrict__ bias,
                                                      uint4* __restrict__ outf, int n) {
    int half = blockIdx.x & 1;
    int lane = threadIdx.x & 63;
    int q = lane >> 3;          // edge slot 0..7
    int fl = lane & 7;          // feat chunk within half: feats half*64+fl*8..+7
    int v = (blockIdx.x >> 1) * 4 + (threadIdx.x >> 6);
    if (v >= n) return;
    float dv = dinv[v];
    int e0 = offs[v], e1 = offs[v + 1];
    int cntE = e1 - e0;
    int nfull = cntE >> 4;
    const char* Hb = (const char*)H + (size_t)half * n * 128 + fl * 16;
    __half2 acc[4];
    __half2 zh = __floats2half2_rn(0.f, 0.f);
    acc[0] = zh; acc[1] = zh; acc[2] = zh; acc[3] = zh;
    int e = e0 + q;
    for (int i = 0; i < nfull; ++i, e += 16) {
        #pragma unroll
        for (int j = 0; j < 2; ++j) {
            int2 p = esw[e + 8 * j];
            __half2 w2 = *(__half2*)&p.y;
            uint4 hq = *(const uint4*)(Hb + ((size_t)(unsigned)p.x << 7));
            const __half2* h2 = (const __half2*)&hq;
            acc[0] = __hfma2(h2[0], w2, acc[0]);
            acc[1] = __hfma2(h2[1], w2, acc[1]);
            acc[2] = __hfma2(h2[2], w2, acc[2]);
            acc[3] = __hfma2(h2[3], w2, acc[3]);
        }
    }
    if (cntE & 15) {
        #pragma unroll
        for (int j = 0; j < 2; ++j) {
            int ee = e + 8 * j;
            int2 p = esw[ee];   // esw padded by 16 zero entries past E
            int wi = (ee < e1) ? p.y : 0;
            __half2 w2 = *(__half2*)&wi;
            uint4 hq = *(const uint4*)(Hb + ((size_t)(unsigned)p.x << 7));
            const __half2* h2 = (const __half2*)&hq;
            acc[0] = __hfma2(h2[0], w2, acc[0]);
            acc[1] = __hfma2(h2[1], w2, acc[1]);
            acc[2] = __hfma2(h2[2], w2, acc[2]);
            acc[3] = __hfma2(h2[3], w2, acc[3]);
        }
    }
    // packed cross-slot reduce (slots live in lane bits 3..5)
    #pragma unroll
    for (int m = 8; m <= 32; m <<= 1) {
        #pragma unroll
        for (int k = 0; k < 4; ++k) {
            int ai = *(int*)&acc[k];
            int bi = __shfl_xor(ai, m, 64);
            acc[k] = __hadd2(acc[k], *(__half2*)&bi);
        }
    }
    if (q == 0) {
        float a[8];
        #pragma unroll
        for (int k = 0; k < 4; ++k) {
            float2 f = __half22float2(acc[k]);
            a[2 * k] = f.x; a[2 * k + 1] = f.y;
        }
        uint4 hq = *(const uint4*)(Hb + ((size_t)(unsigned)v << 7));
        const _Float16* hp = (const _Float16*)&hq;
        float b[8];
        *(float4*)&b[0] = *(const float4*)&bias[half * 64 + fl * 8];
        *(float4*)&b[4] = *(const float4*)&bias[half * 64 + fl * 8 + 4];
        float r[8];
        #pragma unroll
        for (int k = 0; k < 8; ++k) {
            float t2 = fmaf((float)hp[k], dv, a[k]);
            r[k] = fmaf(dv, t2, b[k]);
            r[k] = r[k] > 0.f ? r[k] : (__expf(r[k]) - 1.f);
        }
        union { __half2 h2[4]; uint4 u; } pk;
        pk.h2[0] = __floats2half2_rn(r[0], r[1]);
        pk.h2[1] = __floats2half2_rn(r[2], r[3]);
        pk.h2[2] = __floats2half2_rn(r[4], r[5]);
        pk.h2[3] = __floats2half2_rn(r[6], r[7]);
        int kc = half * 8 + fl;   // global feat chunk 0..15
        int blockc = (v >> 4) * 4 + (kc >> 2);
        int l2 = (kc & 3) * 16 + (v & 15);
        outf[(size_t)blockc * 64 + l2] = pk.u;
    }
}

// CSR aggregation, 64 fp16 feats -> fp32 row-major output.
// v_pk_fma_f16 accumulation, fp32 epilogue.
__global__ __launch_bounds__(256) void agg64_kernel(const __half* __restrict__ H,
                                                    const int* __restrict__ offs,
                                                    const int2* __restrict__ esw,
                                                    const float* __restrict__ dinv,
                                                    const float* __restrict__ bias,
                                                    float* __restrict__ out, int n) {
    int lane = threadIdx.x & 63;
    int q = lane >> 3;          // edge slot 0..7
    int fl = lane & 7;          // feature chunk: feats fl*8 .. fl*8+7
    int v = blockIdx.x * 4 + (threadIdx.x >> 6);
    if (v >= n) return;
    float dv = dinv[v];
    int e0 = offs[v], e1 = offs[v + 1];
    int cntE = e1 - e0;
    int nfull = cntE >> 4;
    const char* Hb = (const char*)H + fl * 16;
    __half2 acc[4];
    __half2 zh = __floats2half2_rn(0.f, 0.f);
    acc[0] = zh; acc[1] = zh; acc[2] = zh; acc[3] = zh;
    int e = e0 + q;
    for (int i = 0; i < nfull; ++i, e += 16) {
        #pragma unroll
        for (int j = 0; j < 2; ++j) {
            int2 p = esw[e + 8 * j];
            __half2 w2 = *(__half2*)&p.y;
            uint4 hq = *(const uint4*)(Hb + ((size_t)(unsigned)p.x << 7));
            const __half2* h2 = (const __half2*)&hq;
            acc[0] = __hfma2(h2[0], w2, acc[0]);
            acc[1] = __hfma2(h2[1], w2, acc[1]);
            acc[2] = __hfma2(h2[2], w2, acc[2]);
            acc[3] = __hfma2(h2[3], w2, acc[3]);
        }
    }
    if (cntE & 15) {
        #pragma unroll
        for (int j = 0; j < 2; ++j) {
            int ee = e + 8 * j;
            int2 p = esw[ee];   // padded past E
            int wi = (ee < e1) ? p.y : 0;
            __half2 w2 = *(__half2*)&wi;
            uint4 hq = *(const uint4*)(Hb + ((size_t)(unsigned)p.x << 7));
            const __half2* h2 = (const __half2*)&hq;
            acc[0] = __hfma2(h2[0], w2, acc[0]);
            acc[1] = __hfma2(h2[1], w2, acc[1]);
            acc[2] = __hfma2(h2[2], w2, acc[2]);
            acc[3] = __hfma2(h2[3], w2, acc[3]);
        }
    }
    #pragma unroll
    for (int m = 8; m <= 32; m <<= 1) {
        #pragma unroll
        for (int k = 0; k < 4; ++k) {
            int ai = *(int*)&acc[k];
            int bi = __shfl_xor(ai, m, 64);
            acc[k] = __hadd2(acc[k], *(__half2*)&bi);
        }
    }
    if (q == 0) {
        float a[8];
        #pragma unroll
        for (int k = 0; k < 4; ++k) {
            float2 f = __half22float2(acc[k]);
            a[2 * k] = f.x; a[2 * k + 1] = f.y;
        }
        uint4 hq = *(const uint4*)(Hb + ((size_t)(unsigned)v << 7));
        const _Float16* hp = (const _Float16*)&hq;
        float b[8];
        *(float4*)&b[0] = *(const float4*)&bias[fl * 8];
        *(float4*)&b[4] = *(const float4*)&bias[fl * 8 + 4];
        float r[8];
        #pragma unroll
        for (int k = 0; k < 8; ++k) {
            float t2 = fmaf((float)hp[k], dv, a[k]);
            r[k] = fmaf(dv, t2, b[k]);
        }
        float4 o0, o1;
        o0.x = r[0]; o0.y = r[1]; o0.z = r[2]; o0.w = r[3];
        o1.x = r[4]; o1.y = r[5]; o1.z = r[6]; o1.w = r[7];
        *(float4*)&out[(size_t)v * 64 + fl * 8] = o0;
        *(float4*)&out[(size_t)v * 64 + fl * 8 + 4] = o1;
    }
}

static inline size_t alignup(size_t x) { return (x + 255) & ~(size_t)255; }

extern "C" void kernel_launch(void* const* d_in, const int* in_sizes, int n_in,
                              void* d_out, int out_size, void* d_ws, size_t ws_size,
                              hipStream_t stream) {
    const float* x  = (const float*)d_in[0];
    const int*   ei = (const int*)d_in[1];
    const float* W1 = (const float*)d_in[2];
    const float* b1 = (const float*)d_in[3];
    const float* W2 = (const float*)d_in[4];
    const float* b2 = (const float*)d_in[5];
    const float* W3 = (const float*)d_in[6];
    const float* b3 = (const float*)d_in[7];
    float* out = (float*)d_out;

    const int N = in_sizes[0] / NFEAT_IN;  // 50000 (divisible by 16)
    const int E = in_sizes[1] / 2;         // 800000
    const int* src = ei;
    const int* dst = ei + E;

    // workspace carve
    char* w = (char*)d_ws;
    int* cnt  = (int*)w;  w += alignup((size_t)N * sizeof(int));
    int* rank = (int*)w;  w += alignup((size_t)E * sizeof(int));
    int* offs = (int*)w;  w += alignup((size_t)(N + 1) * sizeof(int));
    float* dinv = (float*)w; w += alignup((size_t)N * sizeof(float));
    int* bsum = (int*)w;  w += alignup((size_t)64 * sizeof(int));
    int2* esw = (int2*)w; w += alignup((size_t)(E + 16) * sizeof(int2));
    __half* fA = (__half*)w; w += alignup((size_t)N * 128 * sizeof(__half));  // frag layout
    __half* hB = (__half*)w; w += alignup((size_t)N * 128 * sizeof(__half));  // 2 half-arrays
    f16x8* wf1 = (f16x8*)w; w += alignup((size_t)2048 * sizeof(f16x8));
    f16x8* wf2 = (f16x8*)w; w += alignup((size_t)2048 * sizeof(f16x8));
    f16x8* wf3 = (f16x8*)w; w += alignup((size_t)1024 * sizeof(f16x8));

    const int nb = (N + SCAN_CHUNK - 1) / SCAN_CHUNK;  // 25 (<= 64 required)
    const int mtiles = N / 16;                          // 3125
    const int egrid = (E / 4 + 255) / 256;              // ~782
    const size_t hstride = (size_t)N * 64;              // half-array stride (elems)

    // --- build CSR + dinv (shared by all 3 layers) ---
    zero_kernel<<<(N / 4 + 255) / 256, 256, 0, stream>>>((int4*)cnt, N / 4, (int4*)(esw + E));
    countrank_kernel<<<egrid, 256, 0, stream>>>(dst, cnt, rank, E);
    reduce_kernel<<<nb, 256, 0, stream>>>(cnt, bsum, N);
    scan3_kernel<<<nb, 256, 0, stream>>>(cnt, bsum, offs, dinv, N, nb);
    fillr_kernel<<<egrid, 256, 0, stream>>>(src, dst, rank, offs, dinv, esw, E);

    // weight fragments (one dispatch) + layer-1 input fragments
    wfrag_kernel<<<20, 256, 0, stream>>>(W1, W2, W3, wf1, wf2, wf3);
    convx_kernel<<<(N * 16 + 255) / 256, 256, 0, stream>>>(x, (f16x8*)fA, N * 16);

    int gemm_grid = (mtiles + 7) / 8;
    int agg128_grid = ((N + 3) / 4) * 2;
    int agg64_grid = (N + 3) / 4;

    // layer 1
    mgemm_kernel<8><<<gemm_grid, 256, 0, stream>>>((const f16x8*)fA, wf1, hB, mtiles, hstride);
    agg128h_kernel<<<agg128_grid, 256, 0, stream>>>(hB, offs, esw, dinv, b1, (uint4*)fA, N);
    // layer 2
    mgemm_kernel<8><<<gemm_grid, 256, 0, stream>>>((const f16x8*)fA, wf2, hB, mtiles, hstride);
    agg128h_kernel<<<agg128_grid, 256, 0, stream>>>(hB, offs, esw, dinv, b2, (uint4*)fA, N);
    // layer 3 (128 -> 64), no ELU
    mgemm_kernel<4><<<gemm_grid, 256, 0, stream>>>((const f16x8*)fA, wf3, hB, mtiles, 0);
    agg64_kernel<<<agg64_grid, 256, 0, stream>>>(hB, offs, esw, dinv, b3, out, N);
}

// Round 16
// 193.248 us; speedup vs baseline: 1.0797x; 1.0797x over previous
//
#include <hip/hip_runtime.h>
#include <hip/hip_fp16.h>
#include <math.h>

// ---------------------------------------------------------------------------
// 3-layer GCN (PyG GCNConv semantics): per layer
//   h = x @ W ; out[v] = dinv[v]*(dinv[v]*h[v] + sum_e dinv[s]*h[s]) + b
// CSR + dinv built once. All hidden state fp16.
// Build: countrank (ONE fabric-atomic pass, rank = returned old count) ->
// scan -> fillr (atomic-free coalesced scatter).
// GEMM = MFMA f16 16x16x32 swapped operands; W pre-converted to fragments.
// agg128 AND agg64: gather + v_pk_fma_f16 accumulation, packed cross-slot
// reduce, fp32 epilogue. [r15's 2-way feature split regressed: FETCH 94->71MB
// but per-wave bytes-in-flight halved -> latency-bound. This r14 config is
// the measured optimum of the traffic-vs-MLP family (r8/r9/r15 bracket it).]
// ---------------------------------------------------------------------------

#define NFEAT_IN 128
#define SCAN_CHUNK 2048

typedef _Float16 f16x8 __attribute__((ext_vector_type(8)));
typedef float f32x4 __attribute__((ext_vector_type(4)));

// zero cnt; also zero the 16 esw padding entries past E
__global__ void zero_kernel(int4* __restrict__ p, int n4, int4* __restrict__ eswpad) {
    int i = blockIdx.x * blockDim.x + threadIdx.x;
    int4 z; z.x = z.y = z.z = z.w = 0;
    if (i < n4) p[i] = z;
    if (i < 8) eswpad[i] = z;
}

// count + rank in one pass: rank[i] = old cnt[dst[i]] (atomic return value)
__global__ __launch_bounds__(256) void countrank_kernel(const int* __restrict__ dst,
                                                        int* __restrict__ cnt,
                                                        int* __restrict__ rank, int E) {
    int i = blockIdx.x * blockDim.x + threadIdx.x;
    int base = i * 4;
    if (base + 4 <= E) {
        int4 d = *(const int4*)&dst[base];
        int4 r;
        r.x = atomicAdd(&cnt[d.x], 1);
        r.y = atomicAdd(&cnt[d.y], 1);
        r.z = atomicAdd(&cnt[d.z], 1);
        r.w = atomicAdd(&cnt[d.w], 1);
        *(int4*)&rank[base] = r;
    } else {
        for (int k = base; k < E; ++k) rank[k] = atomicAdd(&cnt[dst[k]], 1);
    }
}

__global__ __launch_bounds__(256) void reduce_kernel(const int* __restrict__ cnt,
                                                     int* __restrict__ bsum, int n) {
    __shared__ int wtot[4];
    int b = blockIdx.x, t = threadIdx.x;
    int base = b * SCAN_CHUNK + t * 8;
    int s = 0;
    if (base + 8 <= n) {
        int4 a = *(const int4*)&cnt[base];
        int4 c = *(const int4*)&cnt[base + 4];
        s = a.x + a.y + a.z + a.w + c.x + c.y + c.z + c.w;
    } else {
        for (int i = 0; i < 8; ++i) if (base + i < n) s += cnt[base + i];
    }
    int lane = t & 63, wid = t >> 6;
    #pragma unroll
    for (int off = 32; off > 0; off >>= 1) s += __shfl_down(s, off, 64);
    if (lane == 0) wtot[wid] = s;
    __syncthreads();
    if (t == 0) bsum[b] = wtot[0] + wtot[1] + wtot[2] + wtot[3];
}

// local scan within chunk; block derives its own cross-chunk base from bsum
// (nb <= 64); last block writes offs[n]. Writes offs, dinv.
__global__ __launch_bounds__(256) void scan3_kernel(const int* __restrict__ cnt,
                                                    const int* __restrict__ bsum,
                                                    int* __restrict__ offs,
                                                    float* __restrict__ dinv,
                                                    int n, int nb) {
    __shared__ int wtot[4];
    __shared__ int sbase;
    int b = blockIdx.x, t = threadIdx.x;
    if (t < 64) {
        int val = (t < nb) ? bsum[t] : 0;
        int pre = (t < b) ? val : 0;
        int tot = val;
        #pragma unroll
        for (int off = 32; off > 0; off >>= 1) {
            pre += __shfl_down(pre, off, 64);
            tot += __shfl_down(tot, off, 64);
        }
        if (t == 0) {
            sbase = pre;
            if (b == nb - 1) offs[n] = tot;
        }
    }
    int base = b * SCAN_CHUNK + t * 8;
    int v[8];
    #pragma unroll
    for (int i = 0; i < 8; ++i) v[i] = (base + i < n) ? cnt[base + i] : 0;
    int psum[8], s = 0;
    #pragma unroll
    for (int i = 0; i < 8; ++i) { psum[i] = s; s += v[i]; }
    int lane = t & 63, wid = t >> 6;
    int inc = s;
    #pragma unroll
    for (int off = 1; off < 64; off <<= 1) {
        int tt = __shfl_up(inc, off, 64);
        if (lane >= off) inc += tt;
    }
    if (lane == 63) wtot[wid] = inc;
    __syncthreads();
    int wb = 0;
    for (int w = 0; w < wid; ++w) wb += wtot[w];
    int tbase = sbase + wb + (inc - s);
    #pragma unroll
    for (int i = 0; i < 8; ++i) {
        if (base + i < n) {
            offs[base + i] = tbase + psum[i];
            dinv[base + i] = rsqrtf((float)(v[i] + 1));  // +1 self-loop
        }
    }
}

// atomic-free scatter: p = offs[dst] + rank; payload {src, packed half2(w,w)}
__global__ __launch_bounds__(256) void fillr_kernel(const int* __restrict__ src,
                                                    const int* __restrict__ dst,
                                                    const int* __restrict__ rank,
                                                    const int* __restrict__ offs,
                                                    const float* __restrict__ dinv,
                                                    int2* __restrict__ esw, int E) {
    int i = blockIdx.x * blockDim.x + threadIdx.x;
    int base = i * 4;
    if (base + 4 <= E) {
        int4 d = *(const int4*)&dst[base];
        int4 r = *(const int4*)&rank[base];
        int4 s = *(const int4*)&src[base];
        int p0 = offs[d.x] + r.x;
        int p1 = offs[d.y] + r.y;
        int p2 = offs[d.z] + r.z;
        int p3 = offs[d.w] + r.w;
        float w0 = dinv[s.x], w1 = dinv[s.y], w2 = dinv[s.z], w3 = dinv[s.w];
        __half2 h0 = __floats2half2_rn(w0, w0);
        __half2 h1 = __floats2half2_rn(w1, w1);
        __half2 h2 = __floats2half2_rn(w2, w2);
        __half2 h3 = __floats2half2_rn(w3, w3);
        int2 e0; e0.x = s.x; e0.y = *(int*)&h0;
        int2 e1; e1.x = s.y; e1.y = *(int*)&h1;
        int2 e2; e2.x = s.z; e2.y = *(int*)&h2;
        int2 e3; e3.x = s.w; e3.y = *(int*)&h3;
        esw[p0] = e0; esw[p1] = e1; esw[p2] = e2; esw[p3] = e3;
    } else {
        for (int k = base; k < E; ++k) {
            int d = dst[k];
            int p = offs[d] + rank[k];
            int s = src[k];
            float w = dinv[s];
            __half2 h = __floats2half2_rn(w, w);
            int2 e; e.x = s; e.y = *(int*)&h;
            esw[p] = e;
        }
    }
}

// x fp32 row-major -> fragment-chunk fp16 layout
__global__ __launch_bounds__(256) void convx_kernel(const float* __restrict__ x,
                                                    f16x8* __restrict__ Xf, int nchunk) {
    int i = blockIdx.x * blockDim.x + threadIdx.x;
    if (i >= nchunk) return;
    int m = i >> 4, kc = i & 15;
    float4 a = *(const float4*)&x[(size_t)m * 128 + kc * 8];
    float4 b = *(const float4*)&x[(size_t)m * 128 + kc * 8 + 4];
    f16x8 v;
    v[0] = (_Float16)a.x; v[1] = (_Float16)a.y; v[2] = (_Float16)a.z; v[3] = (_Float16)a.w;
    v[4] = (_Float16)b.x; v[5] = (_Float16)b.y; v[6] = (_Float16)b.z; v[7] = (_Float16)b.w;
    int kt = kc >> 2, sub = kc & 3;
    Xf[(size_t)((m >> 4) * 4 + kt) * 64 + sub * 16 + (m & 15)] = v;
}

// All three W -> fp16 A-fragment arrays in ONE dispatch.
__global__ void wfrag_kernel(const float* __restrict__ W1, const float* __restrict__ W2,
                             const float* __restrict__ W3, f16x8* __restrict__ wf1,
                             f16x8* __restrict__ wf2, f16x8* __restrict__ wf3) {
    int b = blockIdx.x;
    const float* W; f16x8* Wf; int NT;
    if (b < 8)       { W = W1; Wf = wf1; NT = 8; }
    else if (b < 16) { W = W2; Wf = wf2; NT = 8; b -= 8; }
    else             { W = W3; Wf = wf3; NT = 4; b -= 16; }
    int c = b * 256 + threadIdx.x;
    if (c >= NT * 256) return;
    int BN = NT * 16;
    int nt = c >> 8;
    int kt = (c >> 6) & 3;
    int l = c & 63;
    int n = nt * 16 + (l & 15);
    int k0 = kt * 32 + (l >> 4) * 8;
    f16x8 v;
    #pragma unroll
    for (int j = 0; j < 8; ++j) v[j] = (_Float16)W[(size_t)(k0 + j) * BN + n];
    Wf[c] = v;
}

// MFMA GEMM: Y[m, 0..BN) fp16 row-major = X(frag) @ Wf(frag). 2 mtiles/wave.
template <int NT>  // BN = NT*16
__global__ __launch_bounds__(256) void mgemm_kernel(const f16x8* __restrict__ Xf,
                                                    const f16x8* __restrict__ Wg,
                                                    __half* __restrict__ Y, int mtiles) {
    constexpr int BN = NT * 16;
    __shared__ f16x8 Wf[NT * 4 * 64];
    int t = threadIdx.x;
    #pragma unroll
    for (int i = 0; i < NT; ++i) Wf[t + i * 256] = Wg[t + i * 256];
    __syncthreads();
    int lane = t & 63;
    int mt0 = blockIdx.x * 8 + (t >> 6) * 2;
    #pragma unroll
    for (int it = 0; it < 2; ++it) {
        int mtile = mt0 + it;
        if (mtile >= mtiles) continue;
        const f16x8* xb = Xf + (size_t)mtile * 4 * 64;
        f16x8 bf[4];
        #pragma unroll
        for (int kt = 0; kt < 4; ++kt) bf[kt] = xb[kt * 64 + lane];
        f32x4 acc[NT];
        #pragma unroll
        for (int nt = 0; nt < NT; ++nt) acc[nt] = (f32x4){0.f, 0.f, 0.f, 0.f};
        #pragma unroll
        for (int kt = 0; kt < 4; ++kt) {
            #pragma unroll
            for (int nt = 0; nt < NT; ++nt) {
                f16x8 af = Wf[(nt * 4 + kt) * 64 + lane];
                acc[nt] = __builtin_amdgcn_mfma_f32_16x16x32_f16(af, bf[kt], acc[nt], 0, 0, 0);
            }
        }
        int m = mtile * 16 + (lane & 15);
        int nc0 = (lane >> 4) * 4;
        #pragma unroll
        for (int nt = 0; nt < NT; ++nt) {
            union { __half2 h2[2]; uint2 u; } pk;
            pk.h2[0] = __floats2half2_rn(acc[nt][0], acc[nt][1]);
            pk.h2[1] = __floats2half2_rn(acc[nt][2], acc[nt][3]);
            *(uint2*)&Y[(size_t)m * BN + nt * 16 + nc0] = pk.u;
        }
    }
}

// CSR aggregation, 128 fp16 feats. Quarter-wave edge slots; v_pk_fma_f16
// accumulation; packed cross-slot reduce; fp32 epilogue + __expf ELU.
// Output: fragment-chunk fp16 for next GEMM.
__global__ __launch_bounds__(256) void agg128_kernel(const __half* __restrict__ H,
                                                     const int* __restrict__ offs,
                                                     const int2* __restrict__ esw,
                                                     const float* __restrict__ dinv,
                                                     const float* __restrict__ bias,
                                                     uint4* __restrict__ outf, int n) {
    int lane = threadIdx.x & 63;
    int q = lane >> 4;          // edge slot 0..3
    int fl = lane & 15;         // feature chunk: feats fl*8 .. fl*8+7
    int v = blockIdx.x * 4 + (threadIdx.x >> 6);
    if (v >= n) return;
    float dv = dinv[v];
    int e0 = offs[v], e1 = offs[v + 1];
    int cntE = e1 - e0;
    int nfull = cntE >> 4;
    const char* Hb = (const char*)H + fl * 16;
    __half2 acc[4];
    __half2 zh = __floats2half2_rn(0.f, 0.f);
    acc[0] = zh; acc[1] = zh; acc[2] = zh; acc[3] = zh;
    int e = e0 + q;
    for (int i = 0; i < nfull; ++i, e += 16) {
        #pragma unroll
        for (int j = 0; j < 4; ++j) {
            int2 p = esw[e + 4 * j];
            __half2 w2 = *(__half2*)&p.y;
            uint4 hq = *(const uint4*)(Hb + ((size_t)(unsigned)p.x << 8));
            const __half2* h2 = (const __half2*)&hq;
            acc[0] = __hfma2(h2[0], w2, acc[0]);
            acc[1] = __hfma2(h2[1], w2, acc[1]);
            acc[2] = __hfma2(h2[2], w2, acc[2]);
            acc[3] = __hfma2(h2[3], w2, acc[3]);
        }
    }
    if (cntE & 15) {
        #pragma unroll
        for (int j = 0; j < 4; ++j) {
            int ee = e + 4 * j;
            int2 p = esw[ee];   // esw padded by 16 zero entries past E
            int wi = (ee < e1) ? p.y : 0;
            __half2 w2 = *(__half2*)&wi;
            uint4 hq = *(const uint4*)(Hb + ((size_t)(unsigned)p.x << 8));
            const __half2* h2 = (const __half2*)&hq;
            acc[0] = __hfma2(h2[0], w2, acc[0]);
            acc[1] = __hfma2(h2[1], w2, acc[1]);
            acc[2] = __hfma2(h2[2], w2, acc[2]);
            acc[3] = __hfma2(h2[3], w2, acc[3]);
        }
    }
    #pragma unroll
    for (int m = 16; m <= 32; m <<= 1) {
        #pragma unroll
        for (int k = 0; k < 4; ++k) {
            int ai = *(int*)&acc[k];
            int bi = __shfl_xor(ai, m, 64);
            acc[k] = __hadd2(acc[k], *(__half2*)&bi);
        }
    }
    if (q == 0) {
        float a[8];
        #pragma unroll
        for (int k = 0; k < 4; ++k) {
            float2 f = __half22float2(acc[k]);
            a[2 * k] = f.x; a[2 * k + 1] = f.y;
        }
        uint4 hq = *(const uint4*)(Hb + ((size_t)(unsigned)v << 8));
        const _Float16* hp = (const _Float16*)&hq;
        float b[8];
        *(float4*)&b[0] = *(const float4*)&bias[fl * 8];
        *(float4*)&b[4] = *(const float4*)&bias[fl * 8 + 4];
        float r[8];
        #pragma unroll
        for (int k = 0; k < 8; ++k) {
            float t2 = fmaf((float)hp[k], dv, a[k]);
            r[k] = fmaf(dv, t2, b[k]);
            r[k] = r[k] > 0.f ? r[k] : (__expf(r[k]) - 1.f);
        }
        union { __half2 h2[4]; uint4 u; } pk;
        pk.h2[0] = __floats2half2_rn(r[0], r[1]);
        pk.h2[1] = __floats2half2_rn(r[2], r[3]);
        pk.h2[2] = __floats2half2_rn(r[4], r[5]);
        pk.h2[3] = __floats2half2_rn(r[6], r[7]);
        int blockc = (v >> 4) * 4 + (fl >> 2);
        int l2 = (fl & 3) * 16 + (v & 15);
        outf[(size_t)blockc * 64 + l2] = pk.u;
    }
}

// CSR aggregation, 64 fp16 feats -> fp32 row-major output.
// v_pk_fma_f16 accumulation, fp32 epilogue.
__global__ __launch_bounds__(256) void agg64_kernel(const __half* __restrict__ H,
                                                    const int* __restrict__ offs,
                                                    const int2* __restrict__ esw,
                                                    const float* __restrict__ dinv,
                                                    const float* __restrict__ bias,
                                                    float* __restrict__ out, int n) {
    int lane = threadIdx.x & 63;
    int q = lane >> 3;          // edge slot 0..7
    int fl = lane & 7;          // feature chunk: feats fl*8 .. fl*8+7
    int v = blockIdx.x * 4 + (threadIdx.x >> 6);
    if (v >= n) return;
    float dv = dinv[v];
    int e0 = offs[v], e1 = offs[v + 1];
    int cntE = e1 - e0;
    int nfull = cntE >> 4;
    const char* Hb = (const char*)H + fl * 16;
    __half2 acc[4];
    __half2 zh = __floats2half2_rn(0.f, 0.f);
    acc[0] = zh; acc[1] = zh; acc[2] = zh; acc[3] = zh;
    int e = e0 + q;
    for (int i = 0; i < nfull; ++i, e += 16) {
        #pragma unroll
        for (int j = 0; j < 2; ++j) {
            int2 p = esw[e + 8 * j];
            __half2 w2 = *(__half2*)&p.y;
            uint4 hq = *(const uint4*)(Hb + ((size_t)(unsigned)p.x << 7));
            const __half2* h2 = (const __half2*)&hq;
            acc[0] = __hfma2(h2[0], w2, acc[0]);
            acc[1] = __hfma2(h2[1], w2, acc[1]);
            acc[2] = __hfma2(h2[2], w2, acc[2]);
            acc[3] = __hfma2(h2[3], w2, acc[3]);
        }
    }
    if (cntE & 15) {
        #pragma unroll
        for (int j = 0; j < 2; ++j) {
            int ee = e + 8 * j;
            int2 p = esw[ee];   // padded past E
            int wi = (ee < e1) ? p.y : 0;
            __half2 w2 = *(__half2*)&wi;
            uint4 hq = *(const uint4*)(Hb + ((size_t)(unsigned)p.x << 7));
            const __half2* h2 = (const __half2*)&hq;
            acc[0] = __hfma2(h2[0], w2, acc[0]);
            acc[1] = __hfma2(h2[1], w2, acc[1]);
            acc[2] = __hfma2(h2[2], w2, acc[2]);
            acc[3] = __hfma2(h2[3], w2, acc[3]);
        }
    }
    #pragma unroll
    for (int m = 8; m <= 32; m <<= 1) {
        #pragma unroll
        for (int k = 0; k < 4; ++k) {
            int ai = *(int*)&acc[k];
            int bi = __shfl_xor(ai, m, 64);
            acc[k] = __hadd2(acc[k], *(__half2*)&bi);
        }
    }
    if (q == 0) {
        float a[8];
        #pragma unroll
        for (int k = 0; k < 4; ++k) {
            float2 f = __half22float2(acc[k]);
            a[2 * k] = f.x; a[2 * k + 1] = f.y;
        }
        uint4 hq = *(const uint4*)(Hb + ((size_t)(unsigned)v << 7));
        const _Float16* hp = (const _Float16*)&hq;
        float b[8];
        *(float4*)&b[0] = *(const float4*)&bias[fl * 8];
        *(float4*)&b[4] = *(const float4*)&bias[fl * 8 + 4];
        float r[8];
        #pragma unroll
        for (int k = 0; k < 8; ++k) {
            float t2 = fmaf((float)hp[k], dv, a[k]);
            r[k] = fmaf(dv, t2, b[k]);
        }
        float4 o0, o1;
        o0.x = r[0]; o0.y = r[1]; o0.z = r[2]; o0.w = r[3];
        o1.x = r[4]; o1.y = r[5]; o1.z = r[6]; o1.w = r[7];
        *(float4*)&out[(size_t)v * 64 + fl * 8] = o0;
        *(float4*)&out[(size_t)v * 64 + fl * 8 + 4] = o1;
    }
}

static inline size_t alignup(size_t x) { return (x + 255) & ~(size_t)255; }

extern "C" void kernel_launch(void* const* d_in, const int* in_sizes, int n_in,
                              void* d_out, int out_size, void* d_ws, size_t ws_size,
                              hipStream_t stream) {
    const float* x  = (const float*)d_in[0];
    const int*   ei = (const int*)d_in[1];
    const float* W1 = (const float*)d_in[2];
    const float* b1 = (const float*)d_in[3];
    const float* W2 = (const float*)d_in[4];
    const float* b2 = (const float*)d_in[5];
    const float* W3 = (const float*)d_in[6];
    const float* b3 = (const float*)d_in[7];
    float* out = (float*)d_out;

    const int N = in_sizes[0] / NFEAT_IN;  // 50000 (divisible by 16)
    const int E = in_sizes[1] / 2;         // 800000
    const int* src = ei;
    const int* dst = ei + E;

    // workspace carve
    char* w = (char*)d_ws;
    int* cnt  = (int*)w;  w += alignup((size_t)N * sizeof(int));
    int* rank = (int*)w;  w += alignup((size_t)E * sizeof(int));
    int* offs = (int*)w;  w += alignup((size_t)(N + 1) * sizeof(int));
    float* dinv = (float*)w; w += alignup((size_t)N * sizeof(float));
    int* bsum = (int*)w;  w += alignup((size_t)64 * sizeof(int));
    int2* esw = (int2*)w; w += alignup((size_t)(E + 16) * sizeof(int2));
    __half* fA = (__half*)w; w += alignup((size_t)N * 128 * sizeof(__half));  // frag layout
    __half* hB = (__half*)w; w += alignup((size_t)N * 128 * sizeof(__half));  // row-major h
    f16x8* wf1 = (f16x8*)w; w += alignup((size_t)2048 * sizeof(f16x8));
    f16x8* wf2 = (f16x8*)w; w += alignup((size_t)2048 * sizeof(f16x8));
    f16x8* wf3 = (f16x8*)w; w += alignup((size_t)1024 * sizeof(f16x8));

    const int nb = (N + SCAN_CHUNK - 1) / SCAN_CHUNK;  // 25 (<= 64 required)
    const int mtiles = N / 16;                          // 3125
    const int egrid = (E / 4 + 255) / 256;              // ~782

    // --- build CSR + dinv (shared by all 3 layers) ---
    zero_kernel<<<(N / 4 + 255) / 256, 256, 0, stream>>>((int4*)cnt, N / 4, (int4*)(esw + E));
    countrank_kernel<<<egrid, 256, 0, stream>>>(dst, cnt, rank, E);
    reduce_kernel<<<nb, 256, 0, stream>>>(cnt, bsum, N);
    scan3_kernel<<<nb, 256, 0, stream>>>(cnt, bsum, offs, dinv, N, nb);
    fillr_kernel<<<egrid, 256, 0, stream>>>(src, dst, rank, offs, dinv, esw, E);

    // weight fragments (one dispatch) + layer-1 input fragments
    wfrag_kernel<<<20, 256, 0, stream>>>(W1, W2, W3, wf1, wf2, wf3);
    convx_kernel<<<(N * 16 + 255) / 256, 256, 0, stream>>>(x, (f16x8*)fA, N * 16);

    int gemm_grid = (mtiles + 7) / 8;
    int agg_grid = (N + 3) / 4;

    // layer 1
    mgemm_kernel<8><<<gemm_grid, 256, 0, stream>>>((const f16x8*)fA, wf1, hB, mtiles);
    agg128_kernel<<<agg_grid, 256, 0, stream>>>(hB, offs, esw, dinv, b1, (uint4*)fA, N);
    // layer 2
    mgemm_kernel<8><<<gemm_grid, 256, 0, stream>>>((const f16x8*)fA, wf2, hB, mtiles);
    agg128_kernel<<<agg_grid, 256, 0, stream>>>(hB, offs, esw, dinv, b2, (uint4*)fA, N);
    // layer 3 (128 -> 64), no ELU
    mgemm_kernel<4><<<gemm_grid, 256, 0, stream>>>((const f16x8*)fA, wf3, hB, mtiles);
    agg64_kernel<<<agg_grid, 256, 0, stream>>>(hB, offs, esw, dinv, b3, out, N);
}